// Round 1
// baseline (93.548 us; speedup 1.0000x reference)
//
#include <hip/hip_runtime.h>

// ArgumentLocalLogits: BS=16, CTX_PER=1024, ARGS_PER=32, KEY_DIM=128, D_MODEL=512
// rows[p] = p>>10 ; logits[p] = dot(Q[p>>10], keys[(p>>15)*1024 + (p&1023)])
// Restructure: logits = (Q @ W^T) @ ctx^T + Q.b
// ws: Qp bf16 [512][512] + qb f32 [512]
// out: [P floats rows-as-float][P floats logits]
//
// R7: main_kernel restructured. Old: K split over 4 waves -> LDS partial-sum
// reduction (2 extra barriers) + ctx staged through LDS despite zero cross-wave
// reuse. New: each wave owns a full-K 16x16 output tile (args half x 16 ctx
// rows), ctx loaded global->reg->cvt->MFMA directly, Qp in padded LDS
// (2-way bank alias = free), ONE barrier per block. Grid 512 (2 blocks/CU).

#define BSZ        16
#define CTX_PER    1024
#define ARGS_PER   32
#define KD         128
#define DM         512
#define N_ARGS     (BSZ * ARGS_PER)    // 512
#define P_TOTAL    (N_ARGS * CTX_PER)  // 524288

typedef __attribute__((ext_vector_type(8))) short short8;
typedef __attribute__((ext_vector_type(4))) float float4v;

__device__ inline short bf16_of(float x) {
    unsigned u = __builtin_bit_cast(unsigned, x);
    unsigned r = (u + 0x7fffu + ((u >> 16) & 1u)) >> 16;   // RNE
    return (short)r;
}

__device__ inline short8 cvt8(float4 lo, float4 hi) {
    short8 r;
    r[0] = bf16_of(lo.x); r[1] = bf16_of(lo.y); r[2] = bf16_of(lo.z); r[3] = bf16_of(lo.w);
    r[4] = bf16_of(hi.x); r[5] = bf16_of(hi.y); r[6] = bf16_of(hi.z); r[7] = bf16_of(hi.w);
    return r;
}

// Qp[a][m] = sum_d arg[a][d] * W[m][d]  (bf16), qb[a] = dot(arg[a], b)
// grid 256: mtile = b>>3 (16 args), ntile = (b&7)*4 + wave (16 W-rows). 1 MFMA tile per wave.
__global__ __launch_bounds__(256) void qproj_kernel(
    const float* __restrict__ arg, const float* __restrict__ W,
    const float* __restrict__ b, short* __restrict__ Qp, float* __restrict__ qb)
{
    const int t = threadIdx.x, lane = t & 63, wave = t >> 6;
    const int mtile = blockIdx.x >> 3;
    const int ntile = (blockIdx.x & 7) * 4 + wave;
    const int n = lane & 15, quad = lane >> 4;

    // A[m=arg][k=d]: m = lane&15, k = quad*8+j
    const float* asrc = arg + (size_t)(mtile * 16 + n) * KD + quad * 8;
    short8 afr[4];
    #pragma unroll
    for (int kt = 0; kt < 4; ++kt)
        afr[kt] = cvt8(*(const float4*)(asrc + kt * 32), *(const float4*)(asrc + kt * 32 + 4));

    // B[k=d][n=W-row]: n = lane&15
    const float* wsrc = W + (size_t)(ntile * 16 + n) * KD + quad * 8;
    float4v acc = {0.f, 0.f, 0.f, 0.f};
    #pragma unroll
    for (int kt = 0; kt < 4; ++kt) {
        short8 bfr = cvt8(*(const float4*)(wsrc + kt * 32), *(const float4*)(wsrc + kt * 32 + 4));
        acc = __builtin_amdgcn_mfma_f32_16x16x32_bf16(afr[kt], bfr, acc, 0, 0, 0);
    }
    // D: col = lane&15 (= W row-in-tile), row = quad*4+r (= arg-in-tile)
    #pragma unroll
    for (int r = 0; r < 4; ++r)
        Qp[(size_t)(mtile * 16 + quad * 4 + r) * DM + ntile * 16 + n] = bf16_of(acc[r]);

    // qb: only one n-group per m-tile computes it
    if ((blockIdx.x & 7) == 0) {
        __shared__ float red[16][17];
        const int al = t >> 4, seg = t & 15;
        const float* qrow = arg + (size_t)(mtile * 16 + al) * KD + seg * 8;
        float p = 0.f;
        #pragma unroll
        for (int j = 0; j < 8; ++j) p += qrow[j] * b[seg * 8 + j];
        red[al][seg] = p;
        __syncthreads();
        if (t < 16) {
            float ssum = 0.f;
            #pragma unroll
            for (int j = 0; j < 16; ++j) ssum += red[t][j];
            qb[mtile * 16 + t] = ssum;
        }
    }
}

// grid 512 = 16 states x 32 chunks of 32 ctx rows. Block = 4 waves, 256 thr.
// Wave w: full K=512 for one 16x16 tile: args (w&1)*16..+16, ctx rows
// chunk*32 + (w>>1)*16 ..+16. No cross-wave reduction; ctx never touches LDS.
// Qp tile (32x512 bf16) in LDS, padded +8 shorts -> 2-way bank alias (free).
__global__ __launch_bounds__(256, 2) void main_kernel(
    const float* __restrict__ ctx, const short* __restrict__ Qp,
    const float* __restrict__ qb, float* __restrict__ out)
{
    __shared__ __align__(16) short Qpl[32][520];   // 33280 B -> 2+ blocks/CU

    const int t = threadIdx.x, lane = t & 63, wave = t >> 6;
    const int s = blockIdx.x >> 5;
    const int chunk = blockIdx.x & 31;

    const int n = lane & 15, quad = lane >> 4;
    const int A16 = (wave & 1) * 16;                 // arg half
    const int rowbase = chunk * 32 + ((wave >> 1) & 1) * 16;  // ctx slice

    // ctx source for this lane: row rowbase+n, dims quad*8 + kt*32 + j
    const float* csrc = ctx + (size_t)(s * CTX_PER + rowbase + n) * DM + quad * 8;

    // hoist first 2 K-steps of ctx: overlaps HBM latency with Qp staging
    const float4 c0lo = *(const float4*)(csrc);
    const float4 c0hi = *(const float4*)(csrc + 4);
    const float4 c1lo = *(const float4*)(csrc + 32);
    const float4 c1hi = *(const float4*)(csrc + 36);

    // stage Qp_s (32x512 bf16 = 32 KB): 2048 16B-units, coalesced
    const short* qsrc = Qp + (size_t)s * 32 * DM;
    #pragma unroll
    for (int i = 0; i < 8; ++i) {
        const int u = i * 256 + t;
        const int row = u >> 6, c = u & 63;
        *(float4*)&Qpl[row][c * 8] = *(const float4*)(qsrc + (size_t)row * DM + c * 8);
    }

    // rows output (constant per arg-row) — independent of LDS, write pre-barrier
    {
        const int a = t >> 3, c4 = (t & 7) * 4;
        const int ga = s * ARGS_PER + a;
        const float gaf = (float)ga;
        float4 rv = make_float4(gaf, gaf, gaf, gaf);
        *(float4*)(out + (size_t)ga * CTX_PER + chunk * 32 + c4) = rv;
    }

    __syncthreads();

    const short* qrow = &Qpl[A16 + n][quad * 8];

    float4v acc = {0.f, 0.f, 0.f, 0.f};
    {   // kt = 0, 1 from hoisted regs
        short8 a0 = *(const short8*)(qrow);
        acc = __builtin_amdgcn_mfma_f32_16x16x32_bf16(a0, cvt8(c0lo, c0hi), acc, 0, 0, 0);
        short8 a1 = *(const short8*)(qrow + 32);
        acc = __builtin_amdgcn_mfma_f32_16x16x32_bf16(a1, cvt8(c1lo, c1hi), acc, 0, 0, 0);
    }
    #pragma unroll
    for (int kt = 2; kt < 16; ++kt) {
        const float4 lo = *(const float4*)(csrc + kt * 32);
        const float4 hi = *(const float4*)(csrc + kt * 32 + 4);
        short8 bfr = cvt8(lo, hi);
        short8 a  = *(const short8*)(qrow + kt * 32);
        acc = __builtin_amdgcn_mfma_f32_16x16x32_bf16(a, bfr, acc, 0, 0, 0);
    }

    // D: col = lane&15 = ctx row-in-tile (n), row = quad*4+r = arg-in-tile
    const int ga0 = s * ARGS_PER + A16 + quad * 4;
    const float4 qv = *(const float4*)(qb + ga0);    // 16B-aligned (quad*4 floats)
    float* obase = out + P_TOTAL + (size_t)ga0 * CTX_PER + rowbase + n;
    obase[0]           = acc[0] + qv.x;
    obase[CTX_PER]     = acc[1] + qv.y;
    obase[2 * CTX_PER] = acc[2] + qv.z;
    obase[3 * CTX_PER] = acc[3] + qv.w;
}

extern "C" void kernel_launch(void* const* d_in, const int* in_sizes, int n_in,
                              void* d_out, int out_size, void* d_ws, size_t ws_size,
                              hipStream_t stream)
{
    // setup_inputs order: bs, arg_ids, ctx_ids, arg_values, ctx_values, W, b
    const float* arg_values = (const float*)d_in[3];
    const float* ctx_values = (const float*)d_in[4];
    const float* W          = (const float*)d_in[5];
    const float* b          = (const float*)d_in[6];
    float* out = (float*)d_out;

    short* Qp = (short*)d_ws;
    float* qb = (float*)((char*)d_ws + (size_t)N_ARGS * DM * sizeof(short));

    qproj_kernel<<<256, 256, 0, stream>>>(arg_values, W, b, Qp, qb);
    main_kernel<<<BSZ * 32, 256, 0, stream>>>(ctx_values, Qp, qb, out);
}